// Round 9
// baseline (713.261 us; speedup 1.0000x reference)
//
#include <hip/hip_runtime.h>
#include <cmath>

#define B_   16
#define N_   1024
#define KV_  960
#define H_   2
#define LDP  1024                      // padded leading dim for all intermediates
#define PGE  ((size_t)1024 * 1024)    // padded slab stride (elements)

typedef __attribute__((ext_vector_type(8))) short     short8;
typedef __attribute__((ext_vector_type(8))) unsigned short ushort8;
typedef __attribute__((ext_vector_type(4))) unsigned short ushort4v;
typedef __attribute__((ext_vector_type(4))) float     f32x4;
typedef __attribute__((ext_vector_type(4))) float     float4v;
typedef __attribute__((ext_vector_type(2))) float     float2v;

__device__ inline ushort f2b(float f) {
    union { float f; unsigned u; } x; x.f = f;
    unsigned r = x.u + 0x7FFFu + ((x.u >> 16) & 1u);   // RNE
    return (ushort)(r >> 16);
}
__device__ inline float b2f(ushort u) {
    union { unsigned u; float f; } x; x.u = (unsigned)u << 16; return x.f;
}

// Bijective XCD-chunking swizzle (m204).
__device__ inline int xcd_swz(int orig, int nwg) {
    int q = nwg >> 3, r = nwg & 7;
    int xcd = orig & 7, idx = orig >> 3;
    return (xcd < r ? xcd * (q + 1) : r * (q + 1) + (xcd - r) * q) + idx;
}

// async global->LDS, 16B per lane (wave-uniform LDS base + lane*16)
__device__ inline void gload16(const ushort* g, ushort* l) {
    __builtin_amdgcn_global_load_lds(
        (const __attribute__((address_space(1))) void*)g,
        (__attribute__((address_space(3))) void*)l, 16, 0, 0);
}

// ---------------------------------------------------------------------------
// 128x128-tile bf16 MFMA GEMM (m97 structure): BK=32, global_load_lds staging,
// XOR-swizzled LDS, 2-way-free. A: [*][lda] k-contig rows=m. B: [*][ldb]
// k-contig rows=n. Staging may read up to 128 rows (allocate pads!);
// epilogue masks stores to row<mrows, col<ncols. K multiple of 32.
// ---------------------------------------------------------------------------
template<int HSUM, bool OUTF32>
__global__ __launch_bounds__(256)
void gemm128(int gx, int gy, int K, float alpha,
             const ushort* __restrict__ A, int lda, size_t sAb, size_t sAh,
             const ushort* __restrict__ Bm, int ldb, size_t sBb, size_t sBh,
             void* __restrict__ C, int ldc, size_t sCb, size_t sCh,
             int hsel, int mrows, int ncols)
{
    __shared__ ushort As[128 * 32];
    __shared__ ushort Bs[128 * 32];
    const int wgid = xcd_swz(blockIdx.x, gridDim.x);
    const int xg = wgid % gx, rem = wgid / gx;
    const int yg = rem % gy, z = rem / gy;
    int b, h;
    if (hsel >= 0) { b = z; h = hsel; } else { b = z >> 1; h = z & 1; }
    const int m0 = yg * 128, n0 = xg * 128;
    const int t = threadIdx.x, lane = t & 63, wave = t >> 6;
    const int wr = wave >> 1, wc = wave & 1;

    f32x4 acc[4][4];
#pragma unroll
    for (int i = 0; i < 4; ++i)
#pragma unroll
        for (int j = 0; j < 4; ++j) acc[i][j] = f32x4{0.f, 0.f, 0.f, 0.f};

    // staging decode (per-lane global source; linear LDS dest)
    int srow[2], skof[2];
#pragma unroll
    for (int j = 0; j < 2; ++j) {
        int s = wave * 64 + j * 256 + lane;
        srow[j] = s >> 2;
        skof[j] = ((s & 3) ^ ((srow[j] >> 1) & 3)) * 8;
    }
    // ds_read offsets (swizzled), ushort units
    int aoff[4], boff[4];
#pragma unroll
    for (int i = 0; i < 4; ++i) {
        int ra = wr * 64 + i * 16 + (lane & 15);
        aoff[i] = ra * 32 + (((lane >> 4) ^ ((ra >> 1) & 3)) * 8);
        int rb = wc * 64 + i * 16 + (lane & 15);
        boff[i] = rb * 32 + (((lane >> 4) ^ ((rb >> 1) & 3)) * 8);
    }

    for (int hh = 0; hh < HSUM; ++hh) {
        const int he = (HSUM == 2) ? hh : h;
        const ushort* Ab = A + (size_t)b * sAb + (size_t)he * sAh;
        const ushort* Bb = Bm + (size_t)b * sBb + (size_t)he * sBh;
        for (int k0 = 0; k0 < K; k0 += 32) {
#pragma unroll
            for (int j = 0; j < 2; ++j) {
                int sbase = wave * 64 + j * 256;
                gload16(Ab + (size_t)(m0 + srow[j]) * lda + k0 + skof[j], As + sbase * 8);
                gload16(Bb + (size_t)(n0 + srow[j]) * ldb + k0 + skof[j], Bs + sbase * 8);
            }
            __syncthreads();
            short8 a[4], bv[4];
#pragma unroll
            for (int i = 0; i < 4; ++i) {
                a[i]  = *(const short8*)&As[aoff[i]];
                bv[i] = *(const short8*)&Bs[boff[i]];
            }
#pragma unroll
            for (int i = 0; i < 4; ++i)
#pragma unroll
                for (int j = 0; j < 4; ++j)
                    acc[i][j] = __builtin_amdgcn_mfma_f32_16x16x32_bf16(a[i], bv[j], acc[i][j], 0, 0, 0);
            __syncthreads();
        }
    }

    char* Cb = (char*)C + ((size_t)b * sCb + (size_t)h * sCh) * (OUTF32 ? 4 : 2);
#pragma unroll
    for (int i = 0; i < 4; ++i) {
        int row = m0 + wr * 64 + i * 16 + (lane >> 4) * 4;
#pragma unroll
        for (int q = 0; q < 4; ++q) {
            if (row + q >= mrows) continue;
#pragma unroll
            for (int j = 0; j < 4; ++j) {
                int col = n0 + wc * 64 + j * 16 + (lane & 15);
                if (col >= ncols) continue;
                float v = alpha * acc[i][j][q];
                if (OUTF32) ((float*)Cb)[(size_t)(row + q) * ldc + col] = v;
                else        ((ushort*)Cb)[(size_t)(row + q) * ldc + col] = f2b(v);
            }
        }
    }
}

// ---------------------------------------------------------------------------
// f32 -> bf16 dense convert (n % 4 == 0)
// ---------------------------------------------------------------------------
__global__ __launch_bounds__(256)
void cvtf2b(const float* __restrict__ s, ushort* __restrict__ d, size_t n)
{
    size_t i = ((size_t)blockIdx.x * 256 + threadIdx.x) * 4;
    size_t stride = (size_t)gridDim.x * 1024;
    for (; i < n; i += stride) {
        float4v f = *(const float4v*)(s + i);
        ushort4v v;
        v[0] = f2b(f[0]); v[1] = f2b(f[1]); v[2] = f2b(f[2]); v[3] = f2b(f[3]);
        *(ushort4v*)(d + i) = v;
    }
}

// f32 (ld=sld) -> bf16 (ld=dld) re-strided convert; cols=960 (120 x ushort8)
__global__ __launch_bounds__(256)
void cvt_ld(const float* __restrict__ src, int sld, ushort* __restrict__ dst,
            int dld, int total_chunks)
{
    for (int ch = blockIdx.x * 256 + threadIdx.x; ch < total_chunks;
         ch += gridDim.x * 256) {
        int row = ch / 120, c = (ch % 120) * 8;
        const float* s = src + (size_t)row * sld + c;
        float4v f0 = *(const float4v*)s;
        float4v f1 = *(const float4v*)(s + 4);
        ushort8 v;
        v[0] = f2b(f0[0]); v[1] = f2b(f0[1]); v[2] = f2b(f0[2]); v[3] = f2b(f0[3]);
        v[4] = f2b(f1[0]); v[5] = f2b(f1[1]); v[6] = f2b(f1[2]); v[7] = f2b(f1[3]);
        *(ushort8*)(dst + (size_t)row * dld + c) = v;
    }
}

// ---------------------------------------------------------------------------
// Generic f32 [R][C] -> bf16 [C][R] tile transpose+convert.
// grid (C/32, R/32, Z), block (32,8); per-z strides sSrc/sDst (elements).
// ---------------------------------------------------------------------------
__global__ __launch_bounds__(256)
void tposecvt(const float* __restrict__ src, size_t sSrc, int sld,
              ushort* __restrict__ dst, size_t sDst, int dld)
{
    __shared__ ushort tile[32][33];
    const float* s = src + (size_t)blockIdx.z * sSrc;
    ushort* d = dst + (size_t)blockIdx.z * sDst;
    int c0 = blockIdx.x * 32, r0 = blockIdx.y * 32;
    for (int i = threadIdx.y; i < 32; i += 8)
        tile[i][threadIdx.x] = f2b(s[(size_t)(r0 + i) * sld + c0 + threadIdx.x]);
    __syncthreads();
    for (int i = threadIdx.y; i < 32; i += 8)
        d[(size_t)(c0 + i) * dld + r0 + threadIdx.x] = tile[threadIdx.x][i];
}

// ---------------------------------------------------------------------------
// emb_all f32 [n=1024][m=960] -> EA bf16 [n][LDP] AND EAT bf16 [m][LDP] (=^T)
// grid (30, 32, NB), block (32,8). One read pass for both outputs.
// ---------------------------------------------------------------------------
__global__ __launch_bounds__(256)
void dualcvt(const float* __restrict__ src, ushort* __restrict__ ea,
             ushort* __restrict__ eat)
{
    __shared__ ushort tile[32][33];
    const float* s = src + (size_t)blockIdx.z * ((size_t)N_ * KV_);
    ushort* pea  = ea  + (size_t)blockIdx.z * PGE;
    ushort* peat = eat + (size_t)blockIdx.z * PGE;
    int m0 = blockIdx.x * 32, n0 = blockIdx.y * 32;
    for (int i = threadIdx.y; i < 32; i += 8) {
        ushort bv = f2b(s[(size_t)(n0 + i) * KV_ + m0 + threadIdx.x]);
        tile[i][threadIdx.x] = bv;                       // tile[n][m]
        pea[(size_t)(n0 + i) * LDP + m0 + threadIdx.x] = bv;
    }
    __syncthreads();
    for (int i = threadIdx.y; i < 32; i += 8)
        peat[(size_t)(m0 + i) * LDP + n0 + threadIdx.x] = tile[threadIdx.x][i];
}

// ---------------------------------------------------------------------------
// InstanceNorm stats on bf16 scores (LD=LDP, real region only), two-stage.
// ---------------------------------------------------------------------------
__global__ __launch_bounds__(256)
void normstats1(const ushort* __restrict__ S, float2v* __restrict__ partials)
{
    const int z = blockIdx.x, chunk = blockIdx.y;
    const int bh = z >> 2, br = z & 3;
    const int row0[4] = {0, 64, 192, 448};
    const int nch [4] = {1, 2, 4, 8};
    if (chunk >= nch[br]) return;
    const ushort* p = S + (size_t)bh * PGE + (size_t)(row0[br] + chunk * 64) * LDP;
    float s = 0.f, s2 = 0.f;
    for (int ci = threadIdx.x; ci < 64 * 120; ci += 256) {
        int row = ci / 120, c = (ci % 120) * 8;
        ushort8 v = *(const ushort8*)(p + (size_t)row * LDP + c);
#pragma unroll
        for (int j = 0; j < 8; ++j) { float f = b2f(v[j]); s += f; s2 += f * f; }
    }
#pragma unroll
    for (int o = 32; o; o >>= 1) {
        s  += __shfl_down(s,  o);
        s2 += __shfl_down(s2, o);
    }
    __shared__ float as[4], bs[4];
    int w = threadIdx.x >> 6, l = threadIdx.x & 63;
    if (l == 0) { as[w] = s; bs[w] = s2; }
    __syncthreads();
    if (threadIdx.x == 0) {
        float2v r;
        r[0] = as[0] + as[1] + as[2] + as[3];
        r[1] = bs[0] + bs[1] + bs[2] + bs[3];
        partials[z * 8 + chunk] = r;
    }
}

__global__ __launch_bounds__(64)
void normstats2(const float2v* __restrict__ partials, float* __restrict__ stats)
{
    const int z = blockIdx.x;
    const int br = z & 3;
    const int nch[4] = {1, 2, 4, 8};
    const int csz[4] = {64, 128, 256, 512};
    if (threadIdx.x == 0) {
        float s = 0.f, s2 = 0.f;
        for (int i = 0; i < nch[br]; ++i) {
            float2v r = partials[z * 8 + i];
            s += r[0]; s2 += r[1];
        }
        const float inv_cnt = 1.0f / (float)(csz[br] * KV_);
        float mu  = s * inv_cnt;
        float var = s2 * inv_cnt - mu * mu;
        stats[2 * z]     = mu;
        stats[2 * z + 1] = rsqrtf(var + 1e-5f);
    }
}

// ---------------------------------------------------------------------------
// Row softmax, in place on bf16 scores (real 960 cols of LDP-stride rows).
// ---------------------------------------------------------------------------
__global__ __launch_bounds__(256)
void psoftmax(ushort* __restrict__ S, const float* __restrict__ stats)
{
    const int r  = blockIdx.x;
    const int bh  = r / KV_;
    const int row = r % KV_;
    const int br  = (row < 64) ? 0 : (row < 192) ? 1 : (row < 448) ? 2 : 3;
    const float mu = stats[2 * (bh * 4 + br)];
    const float rs = stats[2 * (bh * 4 + br) + 1];
    ushort* p = S + (size_t)bh * PGE + (size_t)row * LDP;

    const int t = threadIdx.x;
    float x[4];
    float mx = -1e30f;
#pragma unroll
    for (int i = 0; i < 4; ++i) {
        int idx = t + i * 256;
        x[i] = (idx < KV_) ? (b2f(p[idx]) - mu) * rs : -1e30f;
        mx = fmaxf(mx, x[i]);
    }
#pragma unroll
    for (int o = 1; o < 64; o <<= 1) mx = fmaxf(mx, __shfl_xor(mx, o));
    __shared__ float wmax[4], wsum[4];
    int w = t >> 6, l = t & 63;
    if (l == 0) wmax[w] = mx;
    __syncthreads();
    mx = fmaxf(fmaxf(wmax[0], wmax[1]), fmaxf(wmax[2], wmax[3]));

    float s = 0.f;
#pragma unroll
    for (int i = 0; i < 4; ++i) {
        x[i] = expf(x[i] - mx);
        s += x[i];
    }
#pragma unroll
    for (int o = 1; o < 64; o <<= 1) s += __shfl_xor(s, o);
    if (l == 0) wsum[w] = s;
    __syncthreads();
    s = wsum[0] + wsum[1] + wsum[2] + wsum[3];
    float inv = 1.0f / s;
#pragma unroll
    for (int i = 0; i < 4; ++i) {
        int idx = t + i * 256;
        if (idx < KV_) p[idx] = f2b(x[i] * inv);
    }
}

// ---------------------------------------------------------------------------
extern "C" void kernel_launch(void* const* d_in, const int* in_sizes, int n_in,
                              void* d_out, int out_size, void* d_ws, size_t ws_size,
                              hipStream_t stream)
{
    const float* emb[4] = {(const float*)d_in[0], (const float*)d_in[1],
                           (const float*)d_in[2], (const float*)d_in[3]};
    const float* emb_all = (const float*)d_in[4];
    const float* Wq[4] = {(const float*)d_in[5], (const float*)d_in[7],
                          (const float*)d_in[9], (const float*)d_in[11]};
    const float* Wo[4] = {(const float*)d_in[6], (const float*)d_in[8],
                          (const float*)d_in[10], (const float*)d_in[12]};
    const float* Wk = (const float*)d_in[13];
    const float* Wv = (const float*)d_in[14];
    float* out = (float*)d_out;

    const int c_sz[4]  = {64, 128, 256, 512};
    const int c_off[4] = {0, 64, 192, 448};
    const int c_pad[4] = {128, 128, 256, 512};   // staging-safe row allocation

    const size_t BN  = (size_t)N_ * KV_;     // 983040
    const size_t GE9 = (size_t)KV_ * KV_;    // 921600
    const float SCALE = 0.03227486121839514f;  // 1/sqrt(960)

    char* wsp = (char*)d_ws;
    size_t off = 0;
    auto alloc = [&](size_t bytes) -> char* {
        off = (off + 255) & ~(size_t)255;
        char* p = wsp + off;
        off += bytes;
        return p;
    };

    // Static: bf16 weights; Wq/Wo rows padded to >=128 for 128-path staging
    ushort* WqB[4]; ushort* WoB[4];
    for (int i = 0; i < 4; ++i) WqB[i] = (ushort*)alloc((size_t)2 * c_pad[i] * c_sz[i] * 2);
    for (int i = 0; i < 4; ++i) WoB[i] = (ushort*)alloc((size_t)c_pad[i] * c_sz[i] * 2);
    ushort* WkB = (ushort*)alloc(2 * PGE * 2);   // [2][1024][LDP]
    ushort* WvT = (ushort*)alloc(2 * PGE * 2);   // [2][m][k] bf16, LD=LDP

    for (int i = 0; i < 4; ++i) {
        size_t n = (size_t)c_sz[i] * c_sz[i];
        for (int hh = 0; hh < 2; ++hh)
            cvtf2b<<<dim3((unsigned)((n / 4 + 255) / 256)), 256, 0, stream>>>(
                Wq[i] + hh * n, WqB[i] + (size_t)hh * c_pad[i] * c_sz[i], n);
        cvtf2b<<<dim3((unsigned)((n / 4 + 255) / 256)), 256, 0, stream>>>(Wo[i], WoB[i], n);
    }
    for (int hh = 0; hh < 2; ++hh)
        cvt_ld<<<dim3(450), 256, 0, stream>>>(Wk + hh * GE9, KV_, WkB + hh * PGE, LDP, 960 * 120);
    tposecvt<<<dim3(30, 30, 2), dim3(32, 8), 0, stream>>>(Wv, GE9, KV_, WvT, PGE, LDP);

    // Per-batch slots: slotA PGE ; Y 2*PGE ; Sc 2*PGE ; EA PGE ; EAT PGE ;
    // embT PGE  => 8*PGE*2B = 16 MB/batch
    const size_t perB = 8 * PGE * 2;
    size_t statik = (off + 255) & ~(size_t)255;
    int NB = 16;
    while (NB > 1 && statik + (size_t)NB * perB + 65536 > ws_size) NB >>= 1;

    ushort* slotA = (ushort*)alloc((size_t)NB * PGE * 2);       // G2 / ctx
    ushort* Y     = (ushort*)alloc((size_t)NB * 2 * PGE * 2);   // Y, then R
    ushort* Sc    = (ushort*)alloc((size_t)NB * 2 * PGE * 2);   // scores/P in place
    ushort* EA    = (ushort*)alloc((size_t)NB * PGE * 2);       // emb_all bf16 [n][m]
    ushort* EAT   = (ushort*)alloc((size_t)NB * PGE * 2);       // emb_all^T bf16 [m][n]
    ushort* embT  = (ushort*)alloc((size_t)NB * PGE * 2);       // emb_cat^T bf16 [p][n]
    float*  stats = (float*) alloc((size_t)NB * 2 * 4 * 2 * 4);
    float2v* parts = (float2v*)alloc((size_t)NB * 2 * 4 * 8 * 8);
    ushort* R = Y;                                              // [NB][1024][LDP]

    for (int b0 = 0; b0 < B_; b0 += NB) {
        // 0) EA [n][m] + EAT [m][n] in one pass ; embT [p][n]
        dualcvt<<<dim3(30, 32, NB), dim3(32, 8), 0, stream>>>(
            emb_all + (size_t)b0 * BN, EA, EAT);
        for (int i = 0; i < 4; ++i)
            tposecvt<<<dim3(c_sz[i] / 32, 32, NB), dim3(32, 8), 0, stream>>>(
                emb[i] + (size_t)b0 * N_ * c_sz[i], (size_t)N_ * c_sz[i], c_sz[i],
                embT + (size_t)c_off[i] * LDP, PGE, LDP);

        // 1) G2[m,p] = sum_n EA[n,m]*emb_cat[n,p]  (128-path, K=1024)
        gemm128<1, false><<<dim3(8 * 8 * NB), 256, 0, stream>>>(
            8, 8, N_, 1.0f,
            EAT, LDP, PGE, 0,
            embT, LDP, PGE, 0,
            slotA, LDP, PGE, 0, /*hsel=*/0, 1024, 1024);

        // 2) Y rows c_off..c_off+c_i = Wq_i[h] @ G2 cols c_off..  (128-path)
        for (int i = 0; i < 4; ++i) {
            int gy = (c_sz[i] + 127) / 128;
            gemm128<1, false><<<dim3(8 * gy * NB * H_), 256, 0, stream>>>(
                8, gy, c_sz[i], 1.0f,
                WqB[i], c_sz[i], 0, (size_t)c_pad[i] * c_sz[i],
                slotA + c_off[i], LDP, PGE, 0,
                Y + (size_t)c_off[i] * LDP, LDP, 2 * PGE, PGE, /*hsel=*/-1,
                c_sz[i], 1024);
        }

        // 3) scores bf16 = SCALE * Y @ Wk[h]^T   (128-path)
        gemm128<1, false><<<dim3(8 * 8 * NB * H_), 256, 0, stream>>>(
            8, 8, KV_, SCALE,
            Y, LDP, 2 * PGE, PGE,
            WkB, LDP, 0, PGE,
            Sc, LDP, 2 * PGE, PGE, /*hsel=*/-1, 1024, 1024);

        // 4) stats + in-place softmax on Sc
        normstats1<<<dim3(NB * H_ * 4, 8), 256, 0, stream>>>(Sc, parts);
        normstats2<<<NB * H_ * 4, 64, 0, stream>>>(parts, stats);
        psoftmax<<<NB * H_ * KV_, 256, 0, stream>>>(Sc, stats);

        // 5) R[p,m] = sum_h P[b,h] @ WvT[h] rows   (128-path, HSUM=2)
        gemm128<2, false><<<dim3(8 * 8 * NB), 256, 0, stream>>>(
            8, 8, KV_, 1.0f,
            Sc, LDP, 2 * PGE, PGE,
            WvT, LDP, 0, PGE,
            R, LDP, PGE, 0, /*hsel=*/0, 1024, 1024);

        // 6) ctx[n,p] = 0.5 * EA @ R^T   (128-path)
        gemm128<1, false><<<dim3(8 * 8 * NB), 256, 0, stream>>>(
            8, 8, KV_, 0.5f,
            EA, LDP, PGE, 0,
            R, LDP, PGE, 0,
            slotA, LDP, PGE, 0, /*hsel=*/0, 1024, 1024);

        // 7) out f32 cols c_off.. = ctx_i @ Wo_i^T   (128-path, masked cols)
        for (int i = 0; i < 4; ++i) {
            int gxb = (c_sz[i] + 127) / 128;
            gemm128<1, true><<<dim3(gxb * 8 * NB), 256, 0, stream>>>(
                gxb, 8, c_sz[i], 1.0f,
                slotA + c_off[i], LDP, PGE, 0,
                WoB[i], c_sz[i], 0, 0,
                out + (size_t)b0 * BN + c_off[i], KV_, BN, 0, /*hsel=*/0,
                1024, c_sz[i]);
        }
    }
}

// Round 11
// 548.317 us; speedup vs baseline: 1.3008x; 1.3008x over previous
//
#include <hip/hip_runtime.h>
#include <cmath>

#define B_   16
#define N_   1024
#define KV_  960
#define H_   2
#define LDP  1024                      // padded leading dim for all intermediates
#define PGE  ((size_t)1024 * 1024)    // padded slab stride (elements)

typedef __attribute__((ext_vector_type(8))) short     short8;
typedef __attribute__((ext_vector_type(8))) unsigned short ushort8;
typedef __attribute__((ext_vector_type(4))) unsigned short ushort4v;
typedef __attribute__((ext_vector_type(4))) float     f32x4;
typedef __attribute__((ext_vector_type(4))) float     float4v;
typedef __attribute__((ext_vector_type(2))) float     float2v;

__device__ inline ushort f2b(float f) {
    union { float f; unsigned u; } x; x.f = f;
    unsigned r = x.u + 0x7FFFu + ((x.u >> 16) & 1u);   // RNE
    return (ushort)(r >> 16);
}
__device__ inline float b2f(ushort u) {
    union { unsigned u; float f; } x; x.u = (unsigned)u << 16; return x.f;
}

// Bijective XCD-chunking swizzle (m204).
__device__ inline int xcd_swz(int orig, int nwg) {
    int q = nwg >> 3, r = nwg & 7;
    int xcd = orig & 7, idx = orig >> 3;
    return (xcd < r ? xcd * (q + 1) : r * (q + 1) + (xcd - r) * q) + idx;
}

// async global->LDS, 16B per lane (wave-uniform LDS base + lane*16)
__device__ inline void gload16(const ushort* g, ushort* l) {
    __builtin_amdgcn_global_load_lds(
        (const __attribute__((address_space(1))) void*)g,
        (__attribute__((address_space(3))) void*)l, 16, 0, 0);
}

// ---------------------------------------------------------------------------
// 128x128-tile bf16 MFMA GEMM, double-buffered: stage(k+1) issued BEFORE
// compute(k); single __syncthreads per K-step (its vmcnt(0) drain lands after
// the 16 MFMAs -> load/compute overlap even at 1 block/CU).
// A,B: [*][LDP] bf16 k-contig. XOR-swizzled LDS (verified 0 conflicts, R8).
// C tuple is (C, ldc, sCb, sCh) — ldc is the ROW stride!
// ---------------------------------------------------------------------------
template<int HSUM, bool OUTF32>
__global__ __launch_bounds__(256)
void gemm128(int gx, int gy, int K, float alpha,
             const ushort* __restrict__ A, size_t sAb, size_t sAh,
             const ushort* __restrict__ Bm, size_t sBb, size_t sBh,
             void* __restrict__ C, int ldc, size_t sCb, size_t sCh, int hsel)
{
    __shared__ ushort As[2][128 * 32];
    __shared__ ushort Bs[2][128 * 32];
    const int wgid = xcd_swz(blockIdx.x, gridDim.x);
    const int xg = wgid % gx, rem = wgid / gx;
    const int yg = rem % gy, z = rem / gy;
    int b, h;
    if (hsel >= 0) { b = z; h = hsel; } else { b = z >> 1; h = z & 1; }
    const int m0 = yg * 128, n0 = xg * 128;
    const int t = threadIdx.x, lane = t & 63, wave = t >> 6;
    const int wr = wave >> 1, wc = wave & 1;

    f32x4 acc[4][4];
#pragma unroll
    for (int i = 0; i < 4; ++i)
#pragma unroll
        for (int j = 0; j < 4; ++j) acc[i][j] = f32x4{0.f, 0.f, 0.f, 0.f};

    // staging decode (per-lane global source; linear LDS dest)
    int srow[2], skof[2];
#pragma unroll
    for (int j = 0; j < 2; ++j) {
        int s = wave * 64 + j * 256 + lane;
        srow[j] = s >> 2;
        skof[j] = ((s & 3) ^ ((srow[j] >> 1) & 3)) * 8;
    }
    // ds_read offsets (swizzled), ushort units
    int aoff[4], boff[4];
#pragma unroll
    for (int i = 0; i < 4; ++i) {
        int ra = wr * 64 + i * 16 + (lane & 15);
        aoff[i] = ra * 32 + (((lane >> 4) ^ ((ra >> 1) & 3)) * 8);
        int rb = wc * 64 + i * 16 + (lane & 15);
        boff[i] = rb * 32 + (((lane >> 4) ^ ((rb >> 1) & 3)) * 8);
    }

    const int ksteps = K >> 5;          // K-steps per head slab
    const int total  = HSUM * ksteps;   // flattened (hh, k) steps

    auto stage = [&](int s, int buf) {
        const int hh = (HSUM == 2) ? (s >= ksteps ? 1 : 0) : h;
        const int k0 = ((HSUM == 2 && s >= ksteps) ? (s - ksteps) : s) << 5;
        const ushort* Ab = A + (size_t)b * sAb + (size_t)hh * sAh;
        const ushort* Bb = Bm + (size_t)b * sBb + (size_t)hh * sBh;
#pragma unroll
        for (int j = 0; j < 2; ++j) {
            int sbase = wave * 64 + j * 256;
            gload16(Ab + (size_t)(m0 + srow[j]) * LDP + k0 + skof[j], &As[buf][sbase * 8]);
            gload16(Bb + (size_t)(n0 + srow[j]) * LDP + k0 + skof[j], &Bs[buf][sbase * 8]);
        }
    };

    stage(0, 0);
    __syncthreads();                    // buf0 resident (vmcnt drained)
    int cur = 0;
    for (int s = 0; s < total; ++s) {
        if (s + 1 < total) stage(s + 1, cur ^ 1);   // async prefetch
        short8 a[4], bv[4];
#pragma unroll
        for (int i = 0; i < 4; ++i) {
            a[i]  = *(const short8*)&As[cur][aoff[i]];
            bv[i] = *(const short8*)&Bs[cur][boff[i]];
        }
#pragma unroll
        for (int i = 0; i < 4; ++i)
#pragma unroll
            for (int j = 0; j < 4; ++j)
                acc[i][j] = __builtin_amdgcn_mfma_f32_16x16x32_bf16(a[i], bv[j], acc[i][j], 0, 0, 0);
        __syncthreads();                // drains prefetch; all reads of cur done
        cur ^= 1;
    }

    char* Cb = (char*)C + ((size_t)b * sCb + (size_t)h * sCh) * (OUTF32 ? 4 : 2);
#pragma unroll
    for (int i = 0; i < 4; ++i) {
        int row = m0 + wr * 64 + i * 16 + (lane >> 4) * 4;
#pragma unroll
        for (int q = 0; q < 4; ++q)
#pragma unroll
            for (int j = 0; j < 4; ++j) {
                int col = n0 + wc * 64 + j * 16 + (lane & 15);
                float v = alpha * acc[i][j][q];
                if (OUTF32) ((float*)Cb)[(size_t)(row + q) * ldc + col] = v;
                else        ((ushort*)Cb)[(size_t)(row + q) * ldc + col] = f2b(v);
            }
    }
}

// ---------------------------------------------------------------------------
// 64x64 tile GEMM (direct staging; steps 2, 7) — R8 known-good.
// ---------------------------------------------------------------------------
template<bool F32S>
__device__ inline void stage64d(const void* __restrict__ src, int ld, int r0, int k0,
                                ushort* __restrict__ lds, int t)
{
#pragma unroll
    for (int rep = 0; rep < 2; ++rep) {
        int idx = t + rep * 256;
        int rr = idx >> 3, kc = (idx & 7) << 3;
        ushort8 v;
        if (F32S) {
            const float* s = (const float*)src + (size_t)(r0 + rr) * ld + (k0 + kc);
            float4v f0 = *(const float4v*)s;
            float4v f1 = *(const float4v*)(s + 4);
            v[0] = f2b(f0[0]); v[1] = f2b(f0[1]); v[2] = f2b(f0[2]); v[3] = f2b(f0[3]);
            v[4] = f2b(f1[0]); v[5] = f2b(f1[1]); v[6] = f2b(f1[2]); v[7] = f2b(f1[3]);
        } else {
            v = *(const ushort8*)((const ushort*)src + (size_t)(r0 + rr) * ld + (k0 + kc));
        }
        *(ushort8*)&lds[rr * 72 + kc] = v;
    }
}

template<bool AF32, bool BF32, int HSUM, bool OUTF32>
__global__ __launch_bounds__(256)
void mgemm(int gx, int gy, int K, float alpha,
           const void* __restrict__ A, int lda, size_t sAb, size_t sAh,
           const void* __restrict__ Bm, int ldb, size_t sBb, size_t sBh,
           void* __restrict__ C, int ldc, size_t sCb, size_t sCh, int hsel)
{
    __shared__ ushort As[64 * 72];
    __shared__ ushort Bs[64 * 72];
    const int wgid = xcd_swz(blockIdx.x, gridDim.x);
    const int xg = wgid % gx, rem = wgid / gx;
    const int yg = rem % gy, z = rem / gy;
    int b, h;
    if (hsel >= 0) { b = z; h = hsel; } else { b = z >> 1; h = z & 1; }
    const int m0 = yg * 64, n0 = xg * 64;
    const int t = threadIdx.x;
    const int lane = t & 63, wave = t >> 6;
    const int wr = wave >> 1, wc = wave & 1;

    f32x4 zero4 = {0.f, 0.f, 0.f, 0.f};
    f32x4 acc[2][2];
    acc[0][0] = zero4; acc[0][1] = zero4; acc[1][0] = zero4; acc[1][1] = zero4;

    for (int hh = 0; hh < HSUM; ++hh) {
        const int he = (HSUM == 2) ? hh : h;
        const char* Ab = (const char*)A + ((size_t)b * sAb + (size_t)he * sAh) * (AF32 ? 4 : 2);
        const char* Bb = (const char*)Bm + ((size_t)b * sBb + (size_t)he * sBh) * (BF32 ? 4 : 2);
        for (int k0 = 0; k0 < K; k0 += 64) {
            stage64d<AF32>(Ab, lda, m0, k0, As, t);
            stage64d<BF32>(Bb, ldb, n0, k0, Bs, t);
            __syncthreads();
            const int ar = wr * 32 + (lane & 15);
            const int br = wc * 32 + (lane & 15);
            const int kg = (lane >> 4) * 8;
#pragma unroll
            for (int ks = 0; ks < 2; ++ks) {
                short8 a0 = *(const short8*)&As[(ar)      * 72 + ks * 32 + kg];
                short8 a1 = *(const short8*)&As[(ar + 16) * 72 + ks * 32 + kg];
                short8 b0 = *(const short8*)&Bs[(br)      * 72 + ks * 32 + kg];
                short8 b1 = *(const short8*)&Bs[(br + 16) * 72 + ks * 32 + kg];
                acc[0][0] = __builtin_amdgcn_mfma_f32_16x16x32_bf16(a0, b0, acc[0][0], 0, 0, 0);
                acc[0][1] = __builtin_amdgcn_mfma_f32_16x16x32_bf16(a0, b1, acc[0][1], 0, 0, 0);
                acc[1][0] = __builtin_amdgcn_mfma_f32_16x16x32_bf16(a1, b0, acc[1][0], 0, 0, 0);
                acc[1][1] = __builtin_amdgcn_mfma_f32_16x16x32_bf16(a1, b1, acc[1][1], 0, 0, 0);
            }
            __syncthreads();
        }
    }

    char* Cb = (char*)C + ((size_t)b * sCb + (size_t)h * sCh) * (OUTF32 ? 4 : 2);
#pragma unroll
    for (int i = 0; i < 2; ++i)
#pragma unroll
        for (int q = 0; q < 4; ++q) {
            int row = m0 + wr * 32 + i * 16 + (lane >> 4) * 4 + q;
#pragma unroll
            for (int j = 0; j < 2; ++j) {
                int col = n0 + wc * 32 + j * 16 + (lane & 15);
                float v = alpha * acc[i][j][q];
                if (OUTF32) ((float*)Cb)[(size_t)row * ldc + col] = v;
                else        ((ushort*)Cb)[(size_t)row * ldc + col] = f2b(v);
            }
        }
}

// ---------------------------------------------------------------------------
// f32 -> bf16 dense convert (n % 4 == 0)
// ---------------------------------------------------------------------------
__global__ __launch_bounds__(256)
void cvtf2b(const float* __restrict__ s, ushort* __restrict__ d, size_t n)
{
    size_t i = ((size_t)blockIdx.x * 256 + threadIdx.x) * 4;
    size_t stride = (size_t)gridDim.x * 1024;
    for (; i < n; i += stride) {
        float4v f = *(const float4v*)(s + i);
        ushort4v v;
        v[0] = f2b(f[0]); v[1] = f2b(f[1]); v[2] = f2b(f[2]); v[3] = f2b(f[3]);
        *(ushort4v*)(d + i) = v;
    }
}

// f32 (ld=sld) -> bf16 (ld=dld) re-strided convert; cols=960 (120 x ushort8)
__global__ __launch_bounds__(256)
void cvt_ld(const float* __restrict__ src, int sld, ushort* __restrict__ dst,
            int dld, int total_chunks)
{
    for (int ch = blockIdx.x * 256 + threadIdx.x; ch < total_chunks;
         ch += gridDim.x * 256) {
        int row = ch / 120, c = (ch % 120) * 8;
        const float* s = src + (size_t)row * sld + c;
        float4v f0 = *(const float4v*)s;
        float4v f1 = *(const float4v*)(s + 4);
        ushort8 v;
        v[0] = f2b(f0[0]); v[1] = f2b(f0[1]); v[2] = f2b(f0[2]); v[3] = f2b(f0[3]);
        v[4] = f2b(f1[0]); v[5] = f2b(f1[1]); v[6] = f2b(f1[2]); v[7] = f2b(f1[3]);
        *(ushort8*)(dst + (size_t)row * dld + c) = v;
    }
}

// ---------------------------------------------------------------------------
// Generic f32 [R][C] -> bf16 [C][R] tile transpose+convert.
// ---------------------------------------------------------------------------
__global__ __launch_bounds__(256)
void tposecvt(const float* __restrict__ src, size_t sSrc, int sld,
              ushort* __restrict__ dst, size_t sDst, int dld)
{
    __shared__ ushort tile[32][33];
    const float* s = src + (size_t)blockIdx.z * sSrc;
    ushort* d = dst + (size_t)blockIdx.z * sDst;
    int c0 = blockIdx.x * 32, r0 = blockIdx.y * 32;
    for (int i = threadIdx.y; i < 32; i += 8)
        tile[i][threadIdx.x] = f2b(s[(size_t)(r0 + i) * sld + c0 + threadIdx.x]);
    __syncthreads();
    for (int i = threadIdx.y; i < 32; i += 8)
        d[(size_t)(c0 + i) * dld + r0 + threadIdx.x] = tile[threadIdx.x][i];
}

// ---------------------------------------------------------------------------
// emb_all f32 [n=1024][m=960] -> EA bf16 [n][LDP] AND EAT bf16 [m][LDP] (=^T)
// ---------------------------------------------------------------------------
__global__ __launch_bounds__(256)
void dualcvt(const float* __restrict__ src, ushort* __restrict__ ea, size_t sEA,
             ushort* __restrict__ eat, size_t sEAT)
{
    __shared__ ushort tile[32][33];
    const float* s = src + (size_t)blockIdx.z * ((size_t)N_ * KV_);
    ushort* pea  = ea  + (size_t)blockIdx.z * sEA;
    ushort* peat = eat + (size_t)blockIdx.z * sEAT;
    int m0 = blockIdx.x * 32, n0 = blockIdx.y * 32;
    for (int i = threadIdx.y; i < 32; i += 8) {
        ushort bv = f2b(s[(size_t)(n0 + i) * KV_ + m0 + threadIdx.x]);
        tile[i][threadIdx.x] = bv;                       // tile[n][m]
        pea[(size_t)(n0 + i) * LDP + m0 + threadIdx.x] = bv;
    }
    __syncthreads();
    for (int i = threadIdx.y; i < 32; i += 8)
        peat[(size_t)(m0 + i) * LDP + n0 + threadIdx.x] = tile[threadIdx.x][i];
}

// ---------------------------------------------------------------------------
// InstanceNorm stats on bf16 scores (LD=LDP, real region only), two-stage.
// ---------------------------------------------------------------------------
__global__ __launch_bounds__(256)
void normstats1(const ushort* __restrict__ S, float2v* __restrict__ partials)
{
    const int z = blockIdx.x, chunk = blockIdx.y;
    const int bh = z >> 2, br = z & 3;
    const int row0[4] = {0, 64, 192, 448};
    const int nch [4] = {1, 2, 4, 8};
    if (chunk >= nch[br]) return;
    const ushort* p = S + (size_t)bh * PGE + (size_t)(row0[br] + chunk * 64) * LDP;
    float s = 0.f, s2 = 0.f;
    for (int ci = threadIdx.x; ci < 64 * 120; ci += 256) {
        int row = ci / 120, c = (ci % 120) * 8;
        ushort8 v = *(const ushort8*)(p + (size_t)row * LDP + c);
#pragma unroll
        for (int j = 0; j < 8; ++j) { float f = b2f(v[j]); s += f; s2 += f * f; }
    }
#pragma unroll
    for (int o = 32; o; o >>= 1) {
        s  += __shfl_down(s,  o);
        s2 += __shfl_down(s2, o);
    }
    __shared__ float as[4], bs[4];
    int w = threadIdx.x >> 6, l = threadIdx.x & 63;
    if (l == 0) { as[w] = s; bs[w] = s2; }
    __syncthreads();
    if (threadIdx.x == 0) {
        float2v r;
        r[0] = as[0] + as[1] + as[2] + as[3];
        r[1] = bs[0] + bs[1] + bs[2] + bs[3];
        partials[z * 8 + chunk] = r;
    }
}

__global__ __launch_bounds__(64)
void normstats2(const float2v* __restrict__ partials, float* __restrict__ stats)
{
    const int z = blockIdx.x;
    const int br = z & 3;
    const int nch[4] = {1, 2, 4, 8};
    const int csz[4] = {64, 128, 256, 512};
    if (threadIdx.x == 0) {
        float s = 0.f, s2 = 0.f;
        for (int i = 0; i < nch[br]; ++i) {
            float2v r = partials[z * 8 + i];
            s += r[0]; s2 += r[1];
        }
        const float inv_cnt = 1.0f / (float)(csz[br] * KV_);
        float mu  = s * inv_cnt;
        float var = s2 * inv_cnt - mu * mu;
        stats[2 * z]     = mu;
        stats[2 * z + 1] = rsqrtf(var + 1e-5f);
    }
}

// ---------------------------------------------------------------------------
// Row softmax, in place on bf16 scores (real 960 cols of LDP-stride rows).
// ---------------------------------------------------------------------------
__global__ __launch_bounds__(256)
void psoftmax(ushort* __restrict__ S, const float* __restrict__ stats)
{
    const int r  = blockIdx.x;
    const int bh  = r / KV_;
    const int row = r % KV_;
    const int br  = (row < 64) ? 0 : (row < 192) ? 1 : (row < 448) ? 2 : 3;
    const float mu = stats[2 * (bh * 4 + br)];
    const float rs = stats[2 * (bh * 4 + br) + 1];
    ushort* p = S + (size_t)bh * PGE + (size_t)row * LDP;

    const int t = threadIdx.x;
    float x[4];
    float mx = -1e30f;
#pragma unroll
    for (int i = 0; i < 4; ++i) {
        int idx = t + i * 256;
        x[i] = (idx < KV_) ? (b2f(p[idx]) - mu) * rs : -1e30f;
        mx = fmaxf(mx, x[i]);
    }
#pragma unroll
    for (int o = 1; o < 64; o <<= 1) mx = fmaxf(mx, __shfl_xor(mx, o));
    __shared__ float wmax[4], wsum[4];
    int w = t >> 6, l = t & 63;
    if (l == 0) wmax[w] = mx;
    __syncthreads();
    mx = fmaxf(fmaxf(wmax[0], wmax[1]), fmaxf(wmax[2], wmax[3]));

    float s = 0.f;
#pragma unroll
    for (int i = 0; i < 4; ++i) {
        x[i] = expf(x[i] - mx);
        s += x[i];
    }
#pragma unroll
    for (int o = 1; o < 64; o <<= 1) s += __shfl_xor(s, o);
    if (l == 0) wsum[w] = s;
    __syncthreads();
    s = wsum[0] + wsum[1] + wsum[2] + wsum[3];
    float inv = 1.0f / s;
#pragma unroll
    for (int i = 0; i < 4; ++i) {
        int idx = t + i * 256;
        if (idx < KV_) p[idx] = f2b(x[i] * inv);
    }
}

// ---------------------------------------------------------------------------
extern "C" void kernel_launch(void* const* d_in, const int* in_sizes, int n_in,
                              void* d_out, int out_size, void* d_ws, size_t ws_size,
                              hipStream_t stream)
{
    const float* emb[4] = {(const float*)d_in[0], (const float*)d_in[1],
                           (const float*)d_in[2], (const float*)d_in[3]};
    const float* emb_all = (const float*)d_in[4];
    const float* Wq[4] = {(const float*)d_in[5], (const float*)d_in[7],
                          (const float*)d_in[9], (const float*)d_in[11]};
    const float* Wo[4] = {(const float*)d_in[6], (const float*)d_in[8],
                          (const float*)d_in[10], (const float*)d_in[12]};
    const float* Wk = (const float*)d_in[13];
    const float* Wv = (const float*)d_in[14];
    float* out = (float*)d_out;

    const int c_sz[4]  = {64, 128, 256, 512};
    const int c_off[4] = {0, 64, 192, 448};

    const size_t BN  = (size_t)N_ * KV_;     // 983040
    const size_t GE9 = (size_t)KV_ * KV_;    // 921600
    const float SCALE = 0.03227486121839514f;  // 1/sqrt(960)

    char* wsp = (char*)d_ws;
    size_t off = 0;
    auto alloc = [&](size_t bytes) -> char* {
        off = (off + 255) & ~(size_t)255;
        char* p = wsp + off;
        off += bytes;
        return p;
    };

    // Static: bf16 weights
    ushort* WqB[4]; ushort* WoB[4];
    for (int i = 0; i < 4; ++i) WqB[i] = (ushort*)alloc((size_t)2 * c_sz[i] * c_sz[i] * 2);
    for (int i = 0; i < 4; ++i) WoB[i] = (ushort*)alloc((size_t)c_sz[i] * c_sz[i] * 2);
    ushort* WkB = (ushort*)alloc(2 * PGE * 2);   // [2][1024][LDP]
    ushort* WvT = (ushort*)alloc(2 * PGE * 2);   // [2][m][k] bf16, LD=LDP

    for (int i = 0; i < 4; ++i) {
        size_t n = (size_t)2 * c_sz[i] * c_sz[i];
        cvtf2b<<<dim3((unsigned)((n / 4 + 255) / 256)), 256, 0, stream>>>(Wq[i], WqB[i], n);
        n = (size_t)c_sz[i] * c_sz[i];
        cvtf2b<<<dim3((unsigned)((n / 4 + 255) / 256)), 256, 0, stream>>>(Wo[i], WoB[i], n);
    }
    for (int hh = 0; hh < 2; ++hh)
        cvt_ld<<<dim3(450), 256, 0, stream>>>(Wk + hh * GE9, KV_, WkB + hh * PGE, LDP, 960 * 120);
    tposecvt<<<dim3(30, 30, 2), dim3(32, 8), 0, stream>>>(Wv, GE9, KV_, WvT, PGE, LDP);

    // Per-batch slots with aliasing: slotA PGE (G2/ctx) ; Y 2*PGE (embT, then
    // Y, then R) ; Sc 2*PGE (EAT, then scores/P) ; EA PGE  => 6*PGE*2B = 12 MB
    const size_t perB = 6 * PGE * 2;
    size_t statik = (off + 255) & ~(size_t)255;
    int NB = 16;
    while (NB > 1 && statik + (size_t)NB * perB + 65536 > ws_size) NB >>= 1;

    ushort* slotA = (ushort*)alloc((size_t)NB * PGE * 2);       // G2 / ctx
    ushort* Y     = (ushort*)alloc((size_t)NB * 2 * PGE * 2);   // embT -> Y -> R
    ushort* Sc    = (ushort*)alloc((size_t)NB * 2 * PGE * 2);   // EAT -> scores/P
    ushort* EA    = (ushort*)alloc((size_t)NB * PGE * 2);       // emb_all bf16 [n][m]
    float*  stats = (float*) alloc((size_t)NB * 2 * 4 * 2 * 4);
    float2v* parts = (float2v*)alloc((size_t)NB * 2 * 4 * 8 * 8);
    ushort* EAT  = Sc;   // [NB][1024][LDP], batch stride 2*PGE — dead after step 1
    ushort* embT = Y;    // [NB][1024][LDP], batch stride 2*PGE — dead after step 1
    ushort* R    = Y;    // [NB][1024][LDP], batch stride 2*PGE after step 5

    for (int b0 = 0; b0 < B_; b0 += NB) {
        // 0) EA [n][m] + EAT [m][n] one pass ; embT [p][n]
        dualcvt<<<dim3(30, 32, NB), dim3(32, 8), 0, stream>>>(
            emb_all + (size_t)b0 * BN, EA, PGE, EAT, 2 * PGE);
        for (int i = 0; i < 4; ++i)
            tposecvt<<<dim3(c_sz[i] / 32, 32, NB), dim3(32, 8), 0, stream>>>(
                emb[i] + (size_t)b0 * N_ * c_sz[i], (size_t)N_ * c_sz[i], c_sz[i],
                embT + (size_t)c_off[i] * LDP, 2 * PGE, LDP);

        // 1) G2[m,p] = sum_n EA[n,m]*emb_cat[n,p]  (128-path, K=1024)
        gemm128<1, false><<<dim3(8 * 8 * NB), 256, 0, stream>>>(
            8, 8, N_, 1.0f,
            EAT, 2 * PGE, 0,
            embT, 2 * PGE, 0,
            slotA, LDP, PGE, 0, /*hsel=*/0);

        // 2) Y rows c_off.. = Wq_i[h] @ G2 cols c_off..  (64-tile)
        for (int i = 0; i < 4; ++i) {
            int gx = KV_ / 64, gy = c_sz[i] / 64;
            mgemm<false, false, 1, false>
                <<<dim3(gx * gy * NB * H_), 256, 0, stream>>>(
                gx, gy, c_sz[i], 1.0f,
                WqB[i], c_sz[i], 0, (size_t)c_sz[i] * c_sz[i],
                slotA + c_off[i], LDP, PGE, 0,
                Y + (size_t)c_off[i] * LDP, LDP, 2 * PGE, PGE, /*hsel=*/-1);
        }

        // 3) scores bf16 = SCALE * Y @ Wk[h]^T   (128-path)
        gemm128<1, false><<<dim3(8 * 8 * NB * H_), 256, 0, stream>>>(
            8, 8, KV_, SCALE,
            Y, 2 * PGE, PGE,
            WkB, 0, PGE,
            Sc, LDP, 2 * PGE, PGE, /*hsel=*/-1);

        // 4) stats + in-place softmax on Sc
        normstats1<<<dim3(NB * H_ * 4, 8), 256, 0, stream>>>(Sc, parts);
        normstats2<<<NB * H_ * 4, 64, 0, stream>>>(parts, stats);
        psoftmax<<<NB * H_ * KV_, 256, 0, stream>>>(Sc, stats);

        // 5) R[p,m] = sum_h P[b,h] @ WvT[h] rows   (128-path, HSUM=2)
        //    C tuple: ldc=LDP (row stride!), batch stride 2*PGE in Y slot.
        gemm128<2, false><<<dim3(8 * 8 * NB), 256, 0, stream>>>(
            8, 8, KV_, 1.0f,
            Sc, 2 * PGE, PGE,
            WvT, 0, PGE,
            R, LDP, 2 * PGE, 0, /*hsel=*/0);

        // 6) ctx[n,p] = 0.5 * EA @ R^T   (128-path)
        gemm128<1, false><<<dim3(8 * 8 * NB), 256, 0, stream>>>(
            8, 8, KV_, 0.5f,
            EA, PGE, 0,
            R, 2 * PGE, 0,
            slotA, LDP, PGE, 0, /*hsel=*/0);

        // 7) out f32 cols c_off.. = ctx_i @ Wo_i^T   (64-tile)
        for (int i = 0; i < 4; ++i) {
            int gx = c_sz[i] / 64, gy = N_ / 64;
            mgemm<false, false, 1, true>
                <<<dim3(gx * gy * NB), 256, 0, stream>>>(
                gx, gy, c_sz[i], 1.0f,
                slotA + c_off[i], LDP, PGE, 0,
                WoB[i], c_sz[i], 0, 0,
                out + (size_t)b0 * BN + c_off[i], KV_, BN, 0, /*hsel=*/0);
        }
    }
}